// Round 2
// baseline (63.997 us; speedup 1.0000x reference)
//
#include <hip/hip_runtime.h>

// Problem constants (fixed by the reference)
#define NUM_CH     5
#define GRID_DIM   32
#define CROP_LO    70          // c - 16 where c = 173/2 = 86
#define CUBES      5
#define VOX_PER_B  (GRID_DIM*GRID_DIM*GRID_DIM)   // 32768

// Gather formulation: one thread per output voxel (per batch), accumulating
// all 5 channels in registers. Exact reference semantics: an atom contributes
// to cell g iff |g - floor(scaled)| <= 5 in every dim (the 11^3 window), with
// val = exp(-0.5 * RES^2 * |scaled - (g+0.5)|^2 / r^2).
// Every output element is written exactly once -> no zero pass, no atomics.
__global__ __launch_bounds__(256) void gather_kernel(
    const float* __restrict__ coords,     // [B, 64, 3]
    const int*   __restrict__ channel,    // [B, 64]
    const float* __restrict__ radius,     // [B, 64]
    float* __restrict__ out)              // [B, 5, 32, 32, 32]
{
    __shared__ float s_sx[64], s_sy[64], s_sz[64], s_kg[64];
    __shared__ int   s_bx[64], s_by[64], s_bz[64], s_ch[64];

    const int b   = blockIdx.x >> 7;                     // 128 blocks per batch
    const int lin = ((blockIdx.x & 127) << 8) | threadIdx.x;  // voxel id in [0,32768)
    const int t   = threadIdx.x;

    if (t < 64) {
        const int a = (b << 6) + t;
        const float sx = coords[3*a + 0] * 4.0f + 86.0f; // (c+20)/0.25 + 6
        const float sy = coords[3*a + 1] * 4.0f + 86.0f;
        const float sz = coords[3*a + 2] * 4.0f + 86.0f;
        const float r  = radius[a];
        s_sx[t] = sx; s_sy[t] = sy; s_sz[t] = sz;
        s_bx[t] = (int)floorf(sx);
        s_by[t] = (int)floorf(sy);
        s_bz[t] = (int)floorf(sz);
        s_kg[t] = -0.03125f / (r * r);                   // -0.5 * RES^2 / r^2
        s_ch[t] = channel[a];
    }
    __syncthreads();

    const int gx = (lin >> 10) + CROP_LO;                // x block-uniform
    const int gy = ((lin >> 5) & 31) + CROP_LO;          // y spans 8 rows per block
    const int gz = (lin & 31) + CROP_LO;                 // z per-lane
    const float fx = (float)gx + 0.5f;
    const float fy = (float)gy + 0.5f;
    const float fz = (float)gz + 0.5f;

    float a0 = 0.f, a1 = 0.f, a2 = 0.f, a3 = 0.f, a4 = 0.f;

    #pragma unroll 4
    for (int a = 0; a < 64; ++a) {
        const bool in =
            (unsigned)(gx - s_bx[a] + CUBES) <= 2u*CUBES &&
            (unsigned)(gy - s_by[a] + CUBES) <= 2u*CUBES &&
            (unsigned)(gz - s_bz[a] + CUBES) <= 2u*CUBES;
        if (in) {   // whole-wave skip via s_cbranch_execz when no lane hits
            const float dx = s_sx[a] - fx;
            const float dy = s_sy[a] - fy;
            const float dz = s_sz[a] - fz;
            const float val = __expf(s_kg[a] * (dx*dx + dy*dy + dz*dz));
            const int ch = s_ch[a];                      // wave-uniform
            a0 += (ch == 0) ? val : 0.f;
            a1 += (ch == 1) ? val : 0.f;
            a2 += (ch == 2) ? val : 0.f;
            a3 += (ch == 3) ? val : 0.f;
            a4 += (ch == 4) ? val : 0.f;
        }
    }

    float* o = out + (size_t)b * NUM_CH * VOX_PER_B + lin;
    o[0*VOX_PER_B] = a0;
    o[1*VOX_PER_B] = a1;
    o[2*VOX_PER_B] = a2;
    o[3*VOX_PER_B] = a3;
    o[4*VOX_PER_B] = a4;
}

extern "C" void kernel_launch(void* const* d_in, const int* in_sizes, int n_in,
                              void* d_out, int out_size, void* d_ws, size_t ws_size,
                              hipStream_t stream) {
    const float* coords  = (const float*)d_in[0];
    const int*   channel = (const int*)d_in[1];
    const float* radius  = (const float*)d_in[2];
    float* out = (float*)d_out;

    const int B = in_sizes[1] / 64;                      // 8
    hipLaunchKernelGGL(gather_kernel, dim3(B * 128), dim3(256), 0, stream,
                       coords, channel, radius, out);
}